// Round 10
// baseline (141.928 us; speedup 1.0000x reference)
//
#include <hip/hip_runtime.h>

// Problem constants
#define BB   4
#define NN   30000
#define TT   12
#define EE   240000
#define FT   24        // F_IN * T floats per (b, node)
#define NM   96        // BB * FT
#define CAP  32        // bucket capacity per node (deg ~ Poisson(8); max ~22)
#define OVCAP 2048     // overflow capacity (normally 0 used)
#define FB   ((EE + 255) / 256)      // 938 fill blocks
#define LOG2E 1.44269504088896340736f

// Workspace layout (4-byte elements), ~4 MB:
//   cnt[NN] @0 | ovc[16] @30000 | eff[256] @30016 | ovf[2*OVCAP] @30272 | bucket @34368
#define WS_CNT 0
#define WS_OVC 30000
#define WS_EFF 30016
#define WS_OVF 30272
#define WS_BKT 34368

__device__ __forceinline__ float readlane_f(float v, int l) {
    return __int_as_float(__builtin_amdgcn_readlane(__float_as_int(v), l));
}

// ---- one launch: bucket-fill | weight fold --------------------------------
// eff layout: Az0[32] Az1[32] ab[32] Ch0[32] Ch1[32] cb[32] probs[12]
// A* = -log2e * (Wz folded), C* = 2*log2e * (Wh folded):
//   u  = exp2(Az0*v0 + Az1*v1 + ab) = exp(-zp)
//   e2 = exp2(Ch0*v0 + Ch1*v1 + cb) = exp(2*hp)
//   (1 - sigmoid(zp)) * tanh(hp) = u*(e2-1) / ((1+u)*(1+e2))
__global__ void __launch_bounds__(256)
k_pre(const int* __restrict__ src, const int* __restrict__ dst,
      const float* __restrict__ czw, const float* __restrict__ czb,
      const float* __restrict__ lzw, const float* __restrict__ lzb,
      const float* __restrict__ chw, const float* __restrict__ chb,
      const float* __restrict__ lhw, const float* __restrict__ lhb,
      const float* __restrict__ att,
      int* __restrict__ cnt, int* __restrict__ ovc,
      int* __restrict__ ovf, int* __restrict__ bucket, float* __restrict__ eff) {
    int bid = blockIdx.x, lt = threadIdx.x;
    if (bid < FB) {
        int e = bid * 256 + lt;
        if (e < EE) {
            int d = dst[e], s = src[e];
            int slot = atomicAdd(&cnt[d], 1);
            if (slot < CAP) {
                bucket[d * CAP + slot] = s;
            } else {
                int o = atomicAdd(ovc, 1);
                if (o < OVCAP) { ovf[2 * o] = d; ovf[2 * o + 1] = s; }
            }
        }
        return;
    }
    // last block: weight folding + attention softmax
    int j = lt;
    if (j < 32) {
        float wz0 = 0.f, wz1 = 0.f, bz = 0.f, wh0 = 0.f, wh1 = 0.f, bh = 0.f;
        for (int k = 0; k < 32; ++k) {
            float lz = lzw[k * 32 + j], lh = lhw[k * 32 + j];
            wz0 = fmaf(czw[k],      lz, wz0);
            wz1 = fmaf(czw[32 + k], lz, wz1);
            bz  = fmaf(czb[k],      lz, bz);
            wh0 = fmaf(chw[k],      lh, wh0);
            wh1 = fmaf(chw[32 + k], lh, wh1);
            bh  = fmaf(chb[k],      lh, bh);
        }
        eff[j]        = -LOG2E * wz0;
        eff[32 + j]   = -LOG2E * wz1;
        eff[64 + j]   = -LOG2E * (bz + lzb[j]);
        eff[96 + j]   = 2.0f * LOG2E * wh0;
        eff[128 + j]  = 2.0f * LOG2E * wh1;
        eff[160 + j]  = 2.0f * LOG2E * (bh + lhb[j]);
    } else if (j == 32) {
        float m = -1e30f;
        for (int t = 0; t < TT; ++t) m = fmaxf(m, att[t]);
        float p[TT], s = 0.f;
        for (int t = 0; t < TT; ++t) { p[t] = __expf(att[t] - m); s += p[t]; }
        float inv = 1.0f / s;
        for (int t = 0; t < TT; ++t) eff[192 + t] = p[t] * inv;
    }
}

// ---- fused gather + gates + head: one wave per node -----------------------
__global__ void __launch_bounds__(256)
k_fused(const float* __restrict__ x, const int* __restrict__ cnt,
        const int* __restrict__ ovc, const int* __restrict__ ovf,
        const int* __restrict__ bucket, const float* __restrict__ eff,
        const float* __restrict__ hw, const float* __restrict__ hb,
        float* __restrict__ out) {
    __shared__ float se[204];       // folded weights + probs
    __shared__ float shwT[384];     // head_w transposed: shwT[k*32 + j]
    __shared__ float shb[12];       // head_b
    __shared__ float sx[4 * NM];    // per-wave aggregated row
    __shared__ float lacc[4 * 128]; // per-wave relu'd hidden (stride 32)
    const int lt = threadIdx.x, lane = lt & 63, w = lt >> 6;
    const int n = blockIdx.x * 4 + w;  // 7500 blocks * 4 waves = 30000 nodes

    if (lt < 204) se[lt] = eff[lt];
    if (lt < 12) shb[lt] = hb[lt];
    for (int i = lt; i < 384; i += 256) {
        int jj = i / 12, kk = i - 12 * jj;
        shwT[kk * 32 + jj] = hw[i];        // transpose: b128-friendly for head
    }
    __syncthreads();

    const bool act = (lane < 48);
    const int b = lane / 12, f2 = lane - 12 * b;       // valid when lane<48
    const float2* xb = (const float2*)x;
    const int lane_off = b * (NN * 12) + f2;           // float2 units

    // per-wave edge list: sv[lane] = source, wv[lane] = rsqrt(deg_s+1)
    // lane m = self loop (sv=n, wv=dn); lanes > m padded with wv=0.
    const int deg = __builtin_amdgcn_readfirstlane(cnt[n]);
    const int m = (deg < CAP) ? deg : CAP;
    int sv = (lane < m) ? bucket[n * CAP + lane] : n;
    float wv = (lane <= m) ? rsqrtf((float)(cnt[sv] + 1)) : 0.f;

    float2 acc = {0.f, 0.f};
    const int total = m + 1;           // including self loop
    int k = 0;
    for (; k + 8 <= total; k += 8) {   // full 8-chunks (1 load round-trip each)
        int s0 = __builtin_amdgcn_readlane(sv, k);
        int s1 = __builtin_amdgcn_readlane(sv, k + 1);
        int s2 = __builtin_amdgcn_readlane(sv, k + 2);
        int s3 = __builtin_amdgcn_readlane(sv, k + 3);
        int s4 = __builtin_amdgcn_readlane(sv, k + 4);
        int s5 = __builtin_amdgcn_readlane(sv, k + 5);
        int s6 = __builtin_amdgcn_readlane(sv, k + 6);
        int s7 = __builtin_amdgcn_readlane(sv, k + 7);
        if (act) {
            float2 v0 = xb[lane_off + s0 * 12];
            float2 v1 = xb[lane_off + s1 * 12];
            float2 v2 = xb[lane_off + s2 * 12];
            float2 v3 = xb[lane_off + s3 * 12];
            float2 v4 = xb[lane_off + s4 * 12];
            float2 v5 = xb[lane_off + s5 * 12];
            float2 v6 = xb[lane_off + s6 * 12];
            float2 v7 = xb[lane_off + s7 * 12];
            float w0 = readlane_f(wv, k),     w1 = readlane_f(wv, k + 1);
            float w2 = readlane_f(wv, k + 2), w3 = readlane_f(wv, k + 3);
            float w4 = readlane_f(wv, k + 4), w5 = readlane_f(wv, k + 5);
            float w6 = readlane_f(wv, k + 6), w7 = readlane_f(wv, k + 7);
            acc.x = fmaf(w0, v0.x, acc.x); acc.y = fmaf(w0, v0.y, acc.y);
            acc.x = fmaf(w1, v1.x, acc.x); acc.y = fmaf(w1, v1.y, acc.y);
            acc.x = fmaf(w2, v2.x, acc.x); acc.y = fmaf(w2, v2.y, acc.y);
            acc.x = fmaf(w3, v3.x, acc.x); acc.y = fmaf(w3, v3.y, acc.y);
            acc.x = fmaf(w4, v4.x, acc.x); acc.y = fmaf(w4, v4.y, acc.y);
            acc.x = fmaf(w5, v5.x, acc.x); acc.y = fmaf(w5, v5.y, acc.y);
            acc.x = fmaf(w6, v6.x, acc.x); acc.y = fmaf(w6, v6.y, acc.y);
            acc.x = fmaf(w7, v7.x, acc.x); acc.y = fmaf(w7, v7.y, acc.y);
        }
    }
    for (; k < total; k += 4) {        // padded 4-chunks (wv=0 beyond total)
        int s0 = __builtin_amdgcn_readlane(sv, k);
        int s1 = __builtin_amdgcn_readlane(sv, k + 1);
        int s2 = __builtin_amdgcn_readlane(sv, k + 2);
        int s3 = __builtin_amdgcn_readlane(sv, k + 3);
        if (act) {
            float2 v0 = xb[lane_off + s0 * 12];
            float2 v1 = xb[lane_off + s1 * 12];
            float2 v2 = xb[lane_off + s2 * 12];
            float2 v3 = xb[lane_off + s3 * 12];
            float w0 = readlane_f(wv, k),     w1 = readlane_f(wv, k + 1);
            float w2 = readlane_f(wv, k + 2), w3 = readlane_f(wv, k + 3);
            acc.x = fmaf(w0, v0.x, acc.x); acc.y = fmaf(w0, v0.y, acc.y);
            acc.x = fmaf(w1, v1.x, acc.x); acc.y = fmaf(w1, v1.y, acc.y);
            acc.x = fmaf(w2, v2.x, acc.x); acc.y = fmaf(w2, v2.y, acc.y);
            acc.x = fmaf(w3, v3.x, acc.x); acc.y = fmaf(w3, v3.y, acc.y);
        }
    }

    // overflow edges (normally zero)
    int nov = __builtin_amdgcn_readfirstlane(*ovc);
    if (nov > 0) {
        if (nov > OVCAP) nov = OVCAP;
        for (int i = 0; i < nov; ++i) {
            int d = ovf[2 * i];
            if (d == n) {
                int s = ovf[2 * i + 1];
                float ws_ = rsqrtf((float)(cnt[s] + 1));
                if (act) {
                    float2 v = xb[lane_off + s * 12];
                    acc.x = fmaf(ws_, v.x, acc.x);
                    acc.y = fmaf(ws_, v.y, acc.y);
                }
            }
        }
    }

    const float dn = readlane_f(wv, m);   // rsqrt(deg_n + 1)
    if (act) {
        float2* sx2 = (float2*)(sx + w * NM + b * FT);
        sx2[f2] = make_float2(dn * acc.x, dn * acc.y);
    }
    __syncthreads();

    // ---- gates: lane handles (b0, j) and (b0+2, j); single-rcp form ----
    const int j = lane & 31, b0_ = lane >> 5;
    const float az0 = se[j],      az1 = se[32 + j],  ab = se[64 + j];
    const float ch0 = se[96 + j], ch1 = se[128 + j], cb = se[160 + j];
#pragma unroll
    for (int bi = 0; bi < 2; ++bi) {
        const int bb = b0_ + 2 * bi;
        const float4* s4 = (const float4*)(sx + w * NM + bb * FT);
        float4 q[6];
#pragma unroll
        for (int i = 0; i < 6; ++i) q[i] = s4[i];   // 6x ds_read_b128
        const float* av = (const float*)q;          // av[0..23] in VGPRs
        float a = 0.f;
#pragma unroll
        for (int t = 0; t < TT; ++t) {
            float v0 = av[t], v1 = av[12 + t], pp = se[192 + t];
            float ae = fmaf(v1, az1, fmaf(v0, az0, ab));     // -zp*log2e
            float ce = fmaf(v1, ch1, fmaf(v0, ch0, cb));     // 2*hp*log2e
            ae = __builtin_amdgcn_fmed3f(ae, -126.f, 126.f);
            ce = __builtin_amdgcn_fmed3f(ce, -126.f, 126.f);
            float u  = __builtin_amdgcn_exp2f(ae);           // exp(-zp)
            float e2 = __builtin_amdgcn_exp2f(ce);           // exp(2*hp)
            float t1  = 1.0f + u;
            float den = fmaf(e2, t1, t1);                    // (1+u)(1+e2)
            float num = fmaf(u, e2, -u);                     // u(e2-1)
            float r   = __builtin_amdgcn_rcpf(den);
            a = fmaf(pp * num, r, a);                        // += p*(1-z)*tanh
        }
        lacc[w * 128 + bb * 32 + j] = fmaxf(a, 0.f);
    }
    __syncthreads();

    // ---- head: lanes 0..47 produce (b, k); all-b128 LDS reads ----
    if (lane < 48) {
        int bb = lane / 12, kk = lane - 12 * bb;
        float r = shb[kk];
        const float4* la4 = (const float4*)(lacc + w * 128 + bb * 32);
        const float4* wt4 = (const float4*)(shwT + kk * 32);
#pragma unroll
        for (int i = 0; i < 8; ++i) {
            float4 a4 = la4[i], w4 = wt4[i];
            r = fmaf(a4.x, w4.x, r); r = fmaf(a4.y, w4.y, r);
            r = fmaf(a4.z, w4.z, r); r = fmaf(a4.w, w4.w, r);
        }
        out[((long long)bb * NN + n) * 12 + kk] = r;
    }
}

extern "C" void kernel_launch(void* const* d_in, const int* in_sizes, int n_in,
                              void* d_out, int out_size, void* d_ws, size_t ws_size,
                              hipStream_t stream) {
    const float* x   = (const float*)d_in[0];
    const int*   ei  = (const int*)d_in[1];     // (2,E): [0,E)=src, [E,2E)=dst
    const float* att = (const float*)d_in[2];
    const float* czw = (const float*)d_in[3];
    const float* czb = (const float*)d_in[4];
    const float* lzw = (const float*)d_in[5];
    const float* lzb = (const float*)d_in[6];
    // d_in[7..10] (conv_r / lin_r) dead: H0 == 0 so H0*R == 0
    const float* chw = (const float*)d_in[11];
    const float* chb = (const float*)d_in[12];
    const float* lhw = (const float*)d_in[13];
    const float* lhb = (const float*)d_in[14];
    const float* hw  = (const float*)d_in[15];
    const float* hb  = (const float*)d_in[16];
    float* out = (float*)d_out;

    float* ws = (float*)d_ws;
    int*   cnt = (int*)(ws + WS_CNT);
    int*   ovc = (int*)(ws + WS_OVC);
    float* eff = ws + WS_EFF;
    int*   ovf = (int*)(ws + WS_OVF);
    int*   bkt = (int*)(ws + WS_BKT);

    const int* src = ei;
    const int* dst = ei + EE;

    hipMemsetAsync(cnt, 0, WS_EFF * 4, stream);   // zero cnt + ovf_cnt
    k_pre<<<FB + 1, 256, 0, stream>>>(src, dst, czw, czb, lzw, lzb,
                                      chw, chb, lhw, lhb, att,
                                      cnt, ovc, ovf, bkt, eff);
    k_fused<<<NN / 4, 256, 0, stream>>>(x, cnt, ovc, ovf, bkt, eff, hw, hb, out);
}